// Round 5
// baseline (229.683 us; speedup 1.0000x reference)
//
#include <hip/hip_runtime.h>
#include <hip/hip_bf16.h>

#define LSEQ 2048
#define NH 16
#define HS 64
#define DIM 1024

typedef __attribute__((ext_vector_type(8))) short short8;
typedef __attribute__((ext_vector_type(4))) float f32x4;

typedef const __attribute__((address_space(1))) void g_void_t;
typedef __attribute__((address_space(3))) void s_void_t;

// 0.125 (1/sqrt(hs)) * log2(e): folded into Q so softmax runs in base 2.
#define QSCALE 0.18033688011112042f

static __device__ __forceinline__ short f2bf(float f) {
  __hip_bfloat16 h = __float2bfloat16(f);
  return __builtin_bit_cast(short, h);
}

static __device__ __forceinline__ float fexp2(float x) {
#if __has_builtin(__builtin_amdgcn_exp2f)
  return __builtin_amdgcn_exp2f(x);
#else
  float r; asm("v_exp_f32 %0, %1" : "=v"(r) : "v"(x)); return r;
#endif
}

// DPP cross-lane move (VALU-only, no LDS pipe).
template<int CTRL>
static __device__ __forceinline__ float dpp_mov(float x) {
  return __builtin_bit_cast(float,
      __builtin_amdgcn_update_dpp(0, __builtin_bit_cast(int, x), CTRL, 0xF, 0xF, true));
}
// Butterfly over 16-lane group with independent masks:
// quad_perm[1,0,3,2]=0xB1, quad_perm[2,3,0,1]=0x4E, row_half_mirror=0x141, row_mirror=0x140.
static __device__ __forceinline__ float redmax16(float x) {
  x = fmaxf(x, dpp_mov<0xB1>(x));
  x = fmaxf(x, dpp_mov<0x4E>(x));
  x = fmaxf(x, dpp_mov<0x141>(x));
  x = fmaxf(x, dpp_mov<0x140>(x));
  return x;
}
static __device__ __forceinline__ float redsum16(float x) {
  x += dpp_mov<0xB1>(x);
  x += dpp_mov<0x4E>(x);
  x += dpp_mov<0x141>(x);
  x += dpp_mov<0x140>(x);
  return x;
}

// ---------------- fused prep kernel (x-cast, Er-cast, Wqkv^T, Wproj^T) ----------------

__global__ void prep_kernel(const float* __restrict__ x, const float* __restrict__ Er,
                            const float* __restrict__ Wqkv, const float* __restrict__ Wproj,
                            short* __restrict__ xb, short* __restrict__ Erb,
                            short* __restrict__ WqkvT, short* __restrict__ WprojT) {
  __shared__ float tile[64][65];
  int bid = blockIdx.x;
  if (bid < 4224) {
    const float* in; short* out; int i0;
    if (bid < 4096) { in = x;  out = xb;  i0 = bid * 256; }
    else            { in = Er; out = Erb; i0 = (bid - 4096) * 256; }
    int i = i0 + threadIdx.x;
    float4 v = reinterpret_cast<const float4*>(in)[i];
    short4 o;
    o.x = f2bf(v.x); o.y = f2bf(v.y); o.z = f2bf(v.z); o.w = f2bf(v.w);
    reinterpret_cast<short4*>(out)[i] = o;
    return;
  }
  int id = bid - 4224;
  const float* W; short* Wt; int N, tx, ty;
  if (id < 768) { W = Wqkv;  Wt = WqkvT;  N = 3072; tx = id % 48; ty = id / 48; }
  else { id -= 768; W = Wproj; Wt = WprojT; N = 1024; tx = id % 16; ty = id / 16; }
  const int K = 1024;
  int k0 = ty * 64, n0 = tx * 64;
  int t = threadIdx.x;
  int r4 = t >> 6, cc = t & 63;
  for (int i = 0; i < 16; ++i) {
    int row = i * 4 + r4;
    tile[row][cc] = W[(size_t)(k0 + row) * N + (n0 + cc)];
  }
  __syncthreads();
  for (int i = 0; i < 16; ++i) {
    int row = i * 4 + r4;
    Wt[(size_t)(n0 + row) * K + (k0 + cc)] = f2bf(tile[cc][row]);
  }
}

// V [bh][2048][64] bf16 -> Vt [bh][64][2048] bf16
__global__ void transpose_v_kernel(const short* __restrict__ V, short* __restrict__ Vt) {
  __shared__ short tile[64][65];
  int bh = blockIdx.y;
  int l0 = blockIdx.x * 64;
  int t = threadIdx.x;
  const short* src = V + ((size_t)bh * LSEQ + l0) * HS;
  for (int i = 0; i < 2; ++i) {
    int ch = i * 256 + t;
    int row = ch >> 3, c8 = ch & 7;
    uint4 v = *reinterpret_cast<const uint4*>(src + row * HS + c8 * 8);
    short tmp[8];
    *reinterpret_cast<uint4*>(tmp) = v;
#pragma unroll
    for (int e = 0; e < 8; ++e) tile[row][c8 * 8 + e] = tmp[e];
  }
  __syncthreads();
  short* dst = Vt + (size_t)bh * HS * LSEQ + l0;
  for (int i = 0; i < 2; ++i) {
    int ch = i * 256 + t;
    int d = ch >> 3, c8 = ch & 7;
    short tmp[8];
#pragma unroll
    for (int e = 0; e < 8; ++e) tmp[e] = tile[c8 * 8 + e][d];
    *reinterpret_cast<uint4*>(dst + (size_t)d * LSEQ + c8 * 8) = *reinterpret_cast<uint4*>(tmp);
  }
}

// ---------------- GEMM (A[M][K] bf16 row-major, Bt[N][K] bf16 row-major) ----------------
// MODE 0: scatter qkv (q pre-scaled by QSCALE). MODE 1: f32 out + bias.

template<int MODE>
__global__ __launch_bounds__(256, 2) void gemm_bt_kernel(
    const short* __restrict__ A, const short* __restrict__ Bt,
    const float* __restrict__ bias, int M, int N, int K,
    short* __restrict__ oq, short* __restrict__ ok, short* __restrict__ ov,
    float* __restrict__ of)
{
  __shared__ short Al[128 * 32];
  __shared__ short Bl[128 * 32];
  const int m0 = blockIdx.y * 128, n0 = blockIdx.x * 128;
  const int t = threadIdx.x;
  const int lane = t & 63, wave = t >> 6;
  const int wr = wave >> 1, wc = wave & 1;
  const int g = lane >> 4, c = lane & 15;
  f32x4 acc[4][4] = {};

  for (int k0 = 0; k0 < K; k0 += 32) {
    __syncthreads();
    for (int i = 0; i < 2; ++i) {
      int ch = i * 256 + t;
      int row = ch >> 2, c8 = ch & 3;
      __builtin_amdgcn_global_load_lds(
          (g_void_t*)(A + (size_t)(m0 + row) * K + k0 + c8 * 8),
          (s_void_t*)(Al + (i * 256 + wave * 64) * 8), 16, 0, 0);
      __builtin_amdgcn_global_load_lds(
          (g_void_t*)(Bt + (size_t)(n0 + row) * K + k0 + c8 * 8),
          (s_void_t*)(Bl + (i * 256 + wave * 64) * 8), 16, 0, 0);
    }
    __syncthreads();
    short8 af[4], bf[4];
#pragma unroll
    for (int mi = 0; mi < 4; ++mi) {
      int row = wr * 64 + mi * 16 + c;
      af[mi] = *reinterpret_cast<const short8*>(Al + row * 32 + g * 8);
    }
#pragma unroll
    for (int ni = 0; ni < 4; ++ni) {
      int row = wc * 64 + ni * 16 + c;
      bf[ni] = *reinterpret_cast<const short8*>(Bl + row * 32 + g * 8);
    }
#pragma unroll
    for (int mi = 0; mi < 4; ++mi)
#pragma unroll
      for (int ni = 0; ni < 4; ++ni)
        acc[mi][ni] = __builtin_amdgcn_mfma_f32_16x16x32_bf16(af[mi], bf[ni], acc[mi][ni], 0, 0, 0);
  }

#pragma unroll
  for (int mi = 0; mi < 4; ++mi)
#pragma unroll
    for (int ni = 0; ni < 4; ++ni) {
      int n = n0 + wc * 64 + ni * 16 + c;
      float bv = bias[n];
#pragma unroll
      for (int r = 0; r < 4; ++r) {
        int m = m0 + wr * 64 + mi * 16 + g * 4 + r;
        float val = acc[mi][ni][r] + bv;
        if (MODE == 0) {
          int which = n >> 10;
          int hh2 = (n >> 6) & 15;
          int d = n & 63;
          int b = m >> 11, ll = m & 2047;
          if (which == 0) val *= QSCALE;
          short* dst = which == 0 ? oq : (which == 1 ? ok : ov);
          dst[(((size_t)b * NH + hh2) * LSEQ + ll) * HS + d] = f2bf(val);
        } else {
          of[(size_t)m * N + n] = val;
        }
      }
    }
}

// ---------------- fused flash attention with relative-position band ----------------
// grid 1024 (heavy-first), wg = one 64-row q-tile, 4 waves x 16 rows, 3 wg/CU.
// K/V^T double-buffered via global_load_lds; Er fragments loaded global->regs
// (L1/L2-hot, shared across heads); ONE barrier per step: stage(s+1) is issued
// after the top barrier of step s, so the same barrier that publishes stage(s)
// also separates iter s-1 reads of buffer sel^1 from iter s writes to it.

__global__ __launch_bounds__(256, 3) void attn_kernel(
    const short* __restrict__ Qb, const short* __restrict__ Kb,
    const short* __restrict__ VTb, const short* __restrict__ Erb,
    short* __restrict__ Y)
{
  const int bid = blockIdx.x;
  const int qt = 31 - (bid >> 5);          // heavy tiles dispatched first
  const int bh = bid & 31;
  const int l0 = qt * 64;
  const int bb = bh >> 4, hh = bh & 15;
  const int t = threadIdx.x;
  const int lane = t & 63, wave = t >> 6;
  const int g = lane >> 4, c = lane & 15;
  const int r8 = lane >> 3;
  const int c16b = (lane & 7) * 16;

  __shared__ short Kl[2][64 * 64];     // 16 KB dbuf
  __shared__ short Vl[2][64 * 64];     // 16 KB dbuf (V^T rows = d)
  __shared__ short Pl[4][16 * 64];     // 8 KB per-wave P

  // ---- Q fragments direct from global (pre-scaled by QSCALE in GEMM1) ----
  const short* Qg = Qb + ((size_t)bh * LSEQ + l0) * HS;
  short8 qf[2];
#pragma unroll
  for (int kk = 0; kk < 2; ++kk)
    qf[kk] = *reinterpret_cast<const short8*>(Qg + (wave * 16 + c) * HS + kk * 32 + g * 8);

  auto stage = [&](int step, int sel) {
    const char* Kg = (const char*)(Kb + ((size_t)bh * LSEQ + step * 64) * HS);
#pragma unroll
    for (int j = 0; j < 2; ++j) {
      int row = wave * 16 + j * 8 + r8;
      __builtin_amdgcn_global_load_lds(
          (g_void_t*)(Kg + row * 128 + (c16b ^ ((row & 7) << 4))),
          (s_void_t*)(&Kl[sel][(wave * 16 + j * 8) * 64]), 16, 0, 0);
    }
#pragma unroll
    for (int j = 0; j < 2; ++j) {
      int row = wave * 16 + j * 8 + r8;  // d index
      const char* Vg = (const char*)(VTb + ((size_t)bh * HS + row) * LSEQ + step * 64);
      __builtin_amdgcn_global_load_lds(
          (g_void_t*)(Vg + (c16b ^ ((row & 7) << 4))),
          (s_void_t*)(&Vl[sel][(wave * 16 + j * 8) * 64]), 16, 0, 0);
    }
  };

  stage(0, 0);

  f32x4 acc_o[4] = {};
  float mrun[4], lrun[4];
#pragma unroll
  for (int r = 0; r < 4; ++r) { mrun[r] = -1e30f; lrun[r] = 0.0f; }

  for (int s = 0; s <= qt; ++s) {
    const int sel = s & 1;
    const bool diag = (s == qt);

    asm volatile("s_waitcnt vmcnt(0)" ::: "memory");   // stage(s) complete
    __builtin_amdgcn_s_barrier();
    __builtin_amdgcn_sched_barrier(0);

    // ---- Er band fragments global->regs (band row e = 1984 + 64*(s-qt) + rb) ----
    // rb = ((3-wave)+s5)*16 + c; e never < 0; clamp high side (masked rows only).
    short8 er[5][2];
    {
      int ebase = 1984 + 64 * (s - qt) + (3 - wave) * 16 + c;
#pragma unroll
      for (int s5 = 0; s5 < 5; ++s5) {
        int e = ebase + s5 * 16;
        if (e > LSEQ - 1) e = LSEQ - 1;
        const short* ep = Erb + (size_t)e * HS + g * 8;
        er[s5][0] = *reinterpret_cast<const short8*>(ep);
        er[s5][1] = *reinterpret_cast<const short8*>(ep + 32);
      }
    }

    if (s < qt) stage(s + 1, sel ^ 1);   // after barrier: safe vs iter s-1 readers

    // ---- G = Q · ErBand^T (5 window subtiles) ----
    f32x4 ga[5];
#pragma unroll
    for (int s5 = 0; s5 < 5; ++s5) {
      ga[s5] = (f32x4){0.0f, 0.0f, 0.0f, 0.0f};
      ga[s5] = __builtin_amdgcn_mfma_f32_16x16x32_bf16(qf[0], er[s5][0], ga[s5], 0, 0, 0);
      ga[s5] = __builtin_amdgcn_mfma_f32_16x16x32_bf16(qf[1], er[s5][1], ga[s5], 0, 0, 0);
    }

    // ---- S = Q K^T ----
    f32x4 sa[4];
#pragma unroll
    for (int ns = 0; ns < 4; ++ns) {
      sa[ns] = (f32x4){0.0f, 0.0f, 0.0f, 0.0f};
#pragma unroll
      for (int kk = 0; kk < 2; ++kk) {
        int row = ns * 16 + c;
        int byte = row * 128 + (((kk * 32 + g * 8) * 2) ^ ((row & 7) << 4));
        short8 kf = *reinterpret_cast<const short8*>((char*)Kl[sel] + byte);
        sa[ns] = __builtin_amdgcn_mfma_f32_16x16x32_bf16(qf[kk], kf, sa[ns], 0, 0, 0);
      }
    }

    // ---- skew + mask ----
    float sv[4][4];
#pragma unroll
    for (int r = 0; r < 4; ++r) {
      int i4 = g * 4 + r;
      int u0 = c + 15 - i4;                // 0..30
      int srcl = (g << 4) | (u0 & 15);
      float bp[5];
#pragma unroll
      for (int s5 = 0; s5 < 5; ++s5) bp[s5] = __shfl(ga[s5][r], srcl, 64);
      bool lo = (u0 < 16);
#pragma unroll
      for (int ns = 0; ns < 4; ++ns) {
        float srel = lo ? bp[ns] : bp[ns + 1];
        float xx = sa[ns][r] + srel;
        if (diag && (ns * 16 + c > wave * 16 + i4)) xx = -1e30f;
        sv[ns][r] = xx;
      }
    }

    // ---- online softmax (DPP reductions, defer-rescale) ----
    float mx[4];
    bool need = false;
#pragma unroll
    for (int r = 0; r < 4; ++r) {
      float m = fmaxf(fmaxf(sv[0][r], sv[1][r]), fmaxf(sv[2][r], sv[3][r]));
      mx[r] = redmax16(m);
      need = need || (mx[r] > mrun[r] + 4.0f);
    }
    if (__ballot(need)) {
#pragma unroll
      for (int r = 0; r < 4; ++r) {
        float mnew = fmaxf(mrun[r], mx[r]);
        float al = fexp2(mrun[r] - mnew);
        mrun[r] = mnew;
        lrun[r] *= al;
#pragma unroll
        for (int ns = 0; ns < 4; ++ns) acc_o[ns][r] *= al;
      }
    }
#pragma unroll
    for (int ns = 0; ns < 4; ++ns)
#pragma unroll
      for (int r = 0; r < 4; ++r)
        sv[ns][r] = fexp2(sv[ns][r] - mrun[r]);
#pragma unroll
    for (int r = 0; r < 4; ++r) {
      float s2 = (sv[0][r] + sv[1][r]) + (sv[2][r] + sv[3][r]);
      lrun[r] += redsum16(s2);
    }

    // ---- P -> LDS (bf16, swizzled, per-wave) ----
    short* Pw = Pl[wave];
#pragma unroll
    for (int ns = 0; ns < 4; ++ns)
#pragma unroll
      for (int r = 0; r < 4; ++r) {
        int row = g * 4 + r;
        int byte = row * 128 + (((ns * 16 + c) * 2) ^ ((row & 7) << 4));
        *reinterpret_cast<short*>(reinterpret_cast<char*>(Pw) + byte) = f2bf(sv[ns][r]);
      }

    // ---- O += P V ----
#pragma unroll
    for (int kk = 0; kk < 2; ++kk) {
      int kbyte = (kk * 32 + g * 8) * 2;
      int byteP = c * 128 + (kbyte ^ ((c & 7) << 4));
      short8 pf = *reinterpret_cast<const short8*>(reinterpret_cast<char*>(Pw) + byteP);
#pragma unroll
      for (int ns = 0; ns < 4; ++ns) {
        int rowV = ns * 16 + c;
        int byteV = rowV * 128 + (kbyte ^ ((rowV & 7) << 4));
        short8 vf = *reinterpret_cast<const short8*>((char*)Vl[sel] + byteV);
        acc_o[ns] = __builtin_amdgcn_mfma_f32_16x16x32_bf16(pf, vf, acc_o[ns], 0, 0, 0);
      }
    }
  }

  // ---- epilogue ----
#pragma unroll
  for (int ns = 0; ns < 4; ++ns)
#pragma unroll
    for (int r = 0; r < 4; ++r) {
      int row = g * 4 + r;
      int lg = l0 + wave * 16 + row;
      int d = ns * 16 + c;
      Y[((size_t)bb * LSEQ + lg) * DIM + hh * HS + d] = f2bf(acc_o[ns][r] / lrun[r]);
    }
}

// ---------------- launch ----------------

extern "C" void kernel_launch(void* const* d_in, const int* in_sizes, int n_in,
                              void* d_out, int out_size, void* d_ws, size_t ws_size,
                              hipStream_t stream)
{
  const float* x     = (const float*)d_in[0];
  const float* Wqkv  = (const float*)d_in[1];
  const float* bqkv  = (const float*)d_in[2];
  const float* Wproj = (const float*)d_in[3];
  const float* bproj = (const float*)d_in[4];
  const float* Er    = (const float*)d_in[5];

  char* ws = (char*)d_ws;
  short* xb     = (short*)(ws + 0);                       // 4096x1024 bf16 (GEMM1 input)
  short* WqkvT  = (short*)(ws + 8388608);                 // 3072x1024 bf16
  short* WprojT = (short*)(ws + 14680064);                // 1024x1024 bf16
  short* Erb    = (short*)(ws + 16777216);                // 2048x64 bf16
  short* qB     = (short*)(ws + 17039360);                // [32][2048][64] bf16
  short* kB     = (short*)(ws + 25427968);
  short* vB     = (short*)(ws + 33816576);
  short* yB     = (short*)(ws + 42205184);                // 4096x1024 bf16
  short* vT     = xb;                                     // reuse xb after GEMM1: [32][64][2048]

  prep_kernel<<<dim3(5248), 256, 0, stream>>>(x, Er, Wqkv, Wproj, xb, Erb, WqkvT, WprojT);

  gemm_bt_kernel<0><<<dim3(3072 / 128, 4096 / 128), 256, 0, stream>>>(
      xb, WqkvT, bqkv, 4096, 3072, 1024, qB, kB, vB, nullptr);

  transpose_v_kernel<<<dim3(32, 32), 256, 0, stream>>>(vB, vT);

  attn_kernel<<<dim3(1024), 256, 0, stream>>>(qB, kB, vT, Erb, yB);

  gemm_bt_kernel<1><<<dim3(1024 / 128, 4096 / 128), 256, 0, stream>>>(
      yB, WprojT, bproj, 4096, 1024, 1024, nullptr, nullptr, nullptr, (float*)d_out);
}

// Round 6
// 147.687 us; speedup vs baseline: 1.5552x; 1.5552x over previous
//
#include <hip/hip_runtime.h>
#include <hip/hip_bf16.h>

#define LSEQ 2048
#define NH 16
#define HS 64
#define DIM 1024

typedef __attribute__((ext_vector_type(8))) short short8;
typedef __attribute__((ext_vector_type(4))) float f32x4;

typedef const __attribute__((address_space(1))) void g_void_t;
typedef __attribute__((address_space(3))) void s_void_t;

// 0.125 (1/sqrt(hs)) * log2(e): folded into Q so softmax runs in base 2.
#define QSCALE 0.18033688011112042f

static __device__ __forceinline__ short f2bf(float f) {
  __hip_bfloat16 h = __float2bfloat16(f);
  return __builtin_bit_cast(short, h);
}

static __device__ __forceinline__ float fexp2(float x) {
#if __has_builtin(__builtin_amdgcn_exp2f)
  return __builtin_amdgcn_exp2f(x);
#else
  float r; asm("v_exp_f32 %0, %1" : "=v"(r) : "v"(x)); return r;
#endif
}

// DPP cross-lane move (VALU-only, no LDS pipe).
template<int CTRL>
static __device__ __forceinline__ float dpp_mov(float x) {
  return __builtin_bit_cast(float,
      __builtin_amdgcn_update_dpp(0, __builtin_bit_cast(int, x), CTRL, 0xF, 0xF, true));
}
// Butterfly over 16-lane group with independent masks:
// quad_perm[1,0,3,2]=0xB1, quad_perm[2,3,0,1]=0x4E, row_half_mirror=0x141, row_mirror=0x140.
static __device__ __forceinline__ float redmax16(float x) {
  x = fmaxf(x, dpp_mov<0xB1>(x));
  x = fmaxf(x, dpp_mov<0x4E>(x));
  x = fmaxf(x, dpp_mov<0x141>(x));
  x = fmaxf(x, dpp_mov<0x140>(x));
  return x;
}
static __device__ __forceinline__ float redsum16(float x) {
  x += dpp_mov<0xB1>(x);
  x += dpp_mov<0x4E>(x);
  x += dpp_mov<0x141>(x);
  x += dpp_mov<0x140>(x);
  return x;
}

// ---------------- fused prep kernel (x-cast, Er-cast, Wqkv^T, Wproj^T) ----------------

__global__ void prep_kernel(const float* __restrict__ x, const float* __restrict__ Er,
                            const float* __restrict__ Wqkv, const float* __restrict__ Wproj,
                            short* __restrict__ xb, short* __restrict__ Erb,
                            short* __restrict__ WqkvT, short* __restrict__ WprojT) {
  __shared__ float tile[64][65];
  int bid = blockIdx.x;
  if (bid < 4224) {
    const float* in; short* out; int i0;
    if (bid < 4096) { in = x;  out = xb;  i0 = bid * 256; }
    else            { in = Er; out = Erb; i0 = (bid - 4096) * 256; }
    int i = i0 + threadIdx.x;
    float4 v = reinterpret_cast<const float4*>(in)[i];
    short4 o;
    o.x = f2bf(v.x); o.y = f2bf(v.y); o.z = f2bf(v.z); o.w = f2bf(v.w);
    reinterpret_cast<short4*>(out)[i] = o;
    return;
  }
  int id = bid - 4224;
  const float* W; short* Wt; int N, tx, ty;
  if (id < 768) { W = Wqkv;  Wt = WqkvT;  N = 3072; tx = id % 48; ty = id / 48; }
  else { id -= 768; W = Wproj; Wt = WprojT; N = 1024; tx = id % 16; ty = id / 16; }
  const int K = 1024;
  int k0 = ty * 64, n0 = tx * 64;
  int t = threadIdx.x;
  int r4 = t >> 6, cc = t & 63;
  for (int i = 0; i < 16; ++i) {
    int row = i * 4 + r4;
    tile[row][cc] = W[(size_t)(k0 + row) * N + (n0 + cc)];
  }
  __syncthreads();
  for (int i = 0; i < 16; ++i) {
    int row = i * 4 + r4;
    Wt[(size_t)(n0 + row) * K + (k0 + cc)] = f2bf(tile[cc][row]);
  }
}

// ---------------- GEMM (A[M][K] bf16 row-major, Bt[N][K] bf16 row-major) ----------------
// MODE 0: scatter q/k row-major (q pre-scaled by QSCALE), v TRANSPOSED [bh][d][l].
// MODE 1: f32 out + bias.

template<int MODE>
__global__ __launch_bounds__(256, 2) void gemm_bt_kernel(
    const short* __restrict__ A, const short* __restrict__ Bt,
    const float* __restrict__ bias, int M, int N, int K,
    short* __restrict__ oq, short* __restrict__ ok, short* __restrict__ ov,
    float* __restrict__ of)
{
  __shared__ short Al[128 * 32];
  __shared__ short Bl[128 * 32];
  const int m0 = blockIdx.y * 128, n0 = blockIdx.x * 128;
  const int t = threadIdx.x;
  const int lane = t & 63, wave = t >> 6;
  const int wr = wave >> 1, wc = wave & 1;
  const int g = lane >> 4, c = lane & 15;
  f32x4 acc[4][4] = {};

  for (int k0 = 0; k0 < K; k0 += 32) {
    __syncthreads();
    for (int i = 0; i < 2; ++i) {
      int ch = i * 256 + t;
      int row = ch >> 2, c8 = ch & 3;
      __builtin_amdgcn_global_load_lds(
          (g_void_t*)(A + (size_t)(m0 + row) * K + k0 + c8 * 8),
          (s_void_t*)(Al + (i * 256 + wave * 64) * 8), 16, 0, 0);
      __builtin_amdgcn_global_load_lds(
          (g_void_t*)(Bt + (size_t)(n0 + row) * K + k0 + c8 * 8),
          (s_void_t*)(Bl + (i * 256 + wave * 64) * 8), 16, 0, 0);
    }
    __syncthreads();
    short8 af[4], bf[4];
#pragma unroll
    for (int mi = 0; mi < 4; ++mi) {
      int row = wr * 64 + mi * 16 + c;
      af[mi] = *reinterpret_cast<const short8*>(Al + row * 32 + g * 8);
    }
#pragma unroll
    for (int ni = 0; ni < 4; ++ni) {
      int row = wc * 64 + ni * 16 + c;
      bf[ni] = *reinterpret_cast<const short8*>(Bl + row * 32 + g * 8);
    }
#pragma unroll
    for (int mi = 0; mi < 4; ++mi)
#pragma unroll
      for (int ni = 0; ni < 4; ++ni)
        acc[mi][ni] = __builtin_amdgcn_mfma_f32_16x16x32_bf16(af[mi], bf[ni], acc[mi][ni], 0, 0, 0);
  }

#pragma unroll
  for (int mi = 0; mi < 4; ++mi)
#pragma unroll
    for (int ni = 0; ni < 4; ++ni) {
      int n = n0 + wc * 64 + ni * 16 + c;
      float bv = bias[n];
#pragma unroll
      for (int r = 0; r < 4; ++r) {
        int m = m0 + wr * 64 + mi * 16 + g * 4 + r;
        float val = acc[mi][ni][r] + bv;
        if (MODE == 0) {
          int which = n >> 10;
          int hh2 = (n >> 6) & 15;
          int d = n & 63;
          int b = m >> 11, ll = m & 2047;
          if (which == 0) {
            oq[(((size_t)b * NH + hh2) * LSEQ + ll) * HS + d] = f2bf(val * QSCALE);
          } else if (which == 1) {
            ok[(((size_t)b * NH + hh2) * LSEQ + ll) * HS + d] = f2bf(val);
          } else {
            // transposed: vT[bh][d][l]; consecutive r -> consecutive l (coalesced)
            ov[(((size_t)b * NH + hh2) * HS + d) * LSEQ + ll] = f2bf(val);
          }
        } else {
          of[(size_t)m * N + n] = val;
        }
      }
    }
}

// ---------------- fused flash attention with relative-position band ----------------
// grid 512: wg = (pair p, bh) processes q-tiles 31-p then p -> 33 steps/wg, balanced.
// K/V^T double-buffered, Er in a 4-slot circular chunk buffer (band start is
// 64-aligned: one new chunk per step). All staging via global_load_lds with
// pre-swizzled source; counted vmcnt(6); 2 barriers/step; DPP softmax; base-2 exp;
// defer-rescale; setprio around MFMA clusters.

__global__ __launch_bounds__(256, 2) void attn_kernel(
    const short* __restrict__ Qb, const short* __restrict__ Kb,
    const short* __restrict__ VTb, const short* __restrict__ Erb,
    short* __restrict__ Y)
{
  const int bid = blockIdx.x;
  const int pair = bid >> 5;
  const int bh = bid & 31;
  const int bb = bh >> 4, hh = bh & 15;
  const int t = threadIdx.x;
  const int lane = t & 63, wave = t >> 6;
  const int g = lane >> 4, c = lane & 15;
  const int r8 = lane >> 3;
  const int c16b = (lane & 7) * 16;

  __shared__ short Ql[64 * 64];            // 8 KB, row-XOR swizzled
  __shared__ short Kl[2][64 * 64];         // 16 KB
  __shared__ short Vl[2][64 * 64];         // 16 KB (V^T rows = d)
  __shared__ short El[4][64 * 64];         // 32 KB, circular, slot = chunk & 3
  __shared__ short Pl[4][16 * 64];         // 8 KB per-wave P

  auto process = [&](int qt) {
    const int l0 = qt * 64;
    const int base = 31 - qt;              // Er chunk window at step s: {base+s, base+s+1}

    // ---- stage Q ----
    const short* Qg = Qb + ((size_t)bh * LSEQ + l0) * HS;
    for (int i = 0; i < 2; ++i) {
      int ch = i * 256 + t;
      int row = ch >> 3, c8 = ch & 7;
      uint4 v = *reinterpret_cast<const uint4*>(Qg + row * HS + c8 * 8);
      int byte = row * 128 + ((c8 * 16) ^ ((row & 7) << 4));
      *reinterpret_cast<uint4*>(reinterpret_cast<char*>(Ql) + byte) = v;
    }
    __syncthreads();

    short8 qf[2];
#pragma unroll
    for (int kk = 0; kk < 2; ++kk) {
      int row = wave * 16 + c;
      int byte = row * 128 + ((kk * 32 + g * 8) * 2 ^ ((row & 7) << 4));
      qf[kk] = *reinterpret_cast<const short8*>(reinterpret_cast<char*>(Ql) + byte);
    }

    f32x4 acc_o[4] = {};
    float mrun[4], lrun[4];
#pragma unroll
    for (int r = 0; r < 4; ++r) { mrun[r] = -1e30f; lrun[r] = 0.0f; }

    auto stage_KV = [&](int step, int sel) {
      const char* Kg = (const char*)(Kb + ((size_t)bh * LSEQ + step * 64) * HS);
#pragma unroll
      for (int j = 0; j < 2; ++j) {
        int row = wave * 16 + j * 8 + r8;
        __builtin_amdgcn_global_load_lds(
            (g_void_t*)(Kg + row * 128 + (c16b ^ ((row & 7) << 4))),
            (s_void_t*)(&Kl[sel][(wave * 16 + j * 8) * 64]), 16, 0, 0);
      }
#pragma unroll
      for (int j = 0; j < 2; ++j) {
        int row = wave * 16 + j * 8 + r8;  // d index
        const char* Vg = (const char*)(VTb + ((size_t)bh * HS + row) * LSEQ + step * 64);
        __builtin_amdgcn_global_load_lds(
            (g_void_t*)(Vg + (c16b ^ ((row & 7) << 4))),
            (s_void_t*)(&Vl[sel][(wave * 16 + j * 8) * 64]), 16, 0, 0);
      }
    };
    auto stage_E = [&](int chunk) {
      int slot = chunk & 3;
#pragma unroll
      for (int j = 0; j < 2; ++j) {
        int row = wave * 16 + j * 8 + r8;          // local row 0..63
        int e = chunk * 64 + row;
        if (e > LSEQ - 1) e = LSEQ - 1;            // clamped rows feed masked cols only
        __builtin_amdgcn_global_load_lds(
            (g_void_t*)((const char*)Erb + (size_t)e * 128 + (c16b ^ ((row & 7) << 4))),
            (s_void_t*)(&El[slot][(wave * 16 + j * 8) * 64]), 16, 0, 0);
      }
    };

    // prologue: K/V for step 0, Er chunks {base, base+1}
    stage_KV(0, 0);
    stage_E(base);
    stage_E(base + 1);

    for (int s = 0; s <= qt; ++s) {
      const int sel = s & 1;
      const bool diag = (s == qt);

      if (s < qt) {
        stage_KV(s + 1, sel ^ 1);          // safe: bottom barrier of s-1 passed
        stage_E(base + s + 2);
        asm volatile("s_waitcnt vmcnt(6)" ::: "memory");
      } else {
        asm volatile("s_waitcnt vmcnt(0)" ::: "memory");
      }
      __builtin_amdgcn_s_barrier();
      __builtin_amdgcn_sched_barrier(0);

      __builtin_amdgcn_s_setprio(1);
      // ---- G = Q · ErBand^T (5 window subtiles; band row rb in circular buffer) ----
      f32x4 ga[5];
#pragma unroll
      for (int s5 = 0; s5 < 5; ++s5) {
        int rb = ((3 - wave) + s5) * 16 + c;       // 0..127
        int phys = (((base + s + (rb >> 6)) & 3) << 6) | (rb & 63);
        ga[s5] = (f32x4){0.0f, 0.0f, 0.0f, 0.0f};
#pragma unroll
        for (int kk = 0; kk < 2; ++kk) {
          int byte = phys * 128 + (((kk * 32 + g * 8) * 2) ^ ((rb & 7) << 4));
          short8 ef = *reinterpret_cast<const short8*>((char*)El + byte);
          ga[s5] = __builtin_amdgcn_mfma_f32_16x16x32_bf16(qf[kk], ef, ga[s5], 0, 0, 0);
        }
      }

      // ---- S = Q K^T ----
      f32x4 sa[4];
#pragma unroll
      for (int ns = 0; ns < 4; ++ns) {
        sa[ns] = (f32x4){0.0f, 0.0f, 0.0f, 0.0f};
#pragma unroll
        for (int kk = 0; kk < 2; ++kk) {
          int row = ns * 16 + c;
          int byte = row * 128 + (((kk * 32 + g * 8) * 2) ^ ((row & 7) << 4));
          short8 kf = *reinterpret_cast<const short8*>((char*)Kl[sel] + byte);
          sa[ns] = __builtin_amdgcn_mfma_f32_16x16x32_bf16(qf[kk], kf, sa[ns], 0, 0, 0);
        }
      }
      __builtin_amdgcn_s_setprio(0);

      // ---- skew + mask ----
      float sv[4][4];
#pragma unroll
      for (int r = 0; r < 4; ++r) {
        int i4 = g * 4 + r;
        int u0 = c + 15 - i4;                // 0..30
        int srcl = (g << 4) | (u0 & 15);
        float bp[5];
#pragma unroll
        for (int s5 = 0; s5 < 5; ++s5) bp[s5] = __shfl(ga[s5][r], srcl, 64);
        bool lo = (u0 < 16);
#pragma unroll
        for (int ns = 0; ns < 4; ++ns) {
          float srel = lo ? bp[ns] : bp[ns + 1];
          float xx = sa[ns][r] + srel;
          if (diag && (ns * 16 + c > wave * 16 + i4)) xx = -1e30f;
          sv[ns][r] = xx;
        }
      }

      // ---- online softmax (DPP reductions, defer-rescale) ----
      float mx[4];
      bool need = false;
#pragma unroll
      for (int r = 0; r < 4; ++r) {
        float m = fmaxf(fmaxf(sv[0][r], sv[1][r]), fmaxf(sv[2][r], sv[3][r]));
        mx[r] = redmax16(m);
        need = need || (mx[r] > mrun[r] + 4.0f);
      }
      if (__ballot(need)) {
#pragma unroll
        for (int r = 0; r < 4; ++r) {
          float mnew = fmaxf(mrun[r], mx[r]);
          float al = fexp2(mrun[r] - mnew);
          mrun[r] = mnew;
          lrun[r] *= al;
#pragma unroll
          for (int ns = 0; ns < 4; ++ns) acc_o[ns][r] *= al;
        }
      }
#pragma unroll
      for (int ns = 0; ns < 4; ++ns)
#pragma unroll
        for (int r = 0; r < 4; ++r)
          sv[ns][r] = fexp2(sv[ns][r] - mrun[r]);
#pragma unroll
      for (int r = 0; r < 4; ++r) {
        float s2 = (sv[0][r] + sv[1][r]) + (sv[2][r] + sv[3][r]);
        lrun[r] += redsum16(s2);
      }

      // ---- P -> LDS (bf16, swizzled, per-wave) ----
      short* Pw = Pl[wave];
#pragma unroll
      for (int ns = 0; ns < 4; ++ns)
#pragma unroll
        for (int r = 0; r < 4; ++r) {
          int row = g * 4 + r;
          int byte = row * 128 + (((ns * 16 + c) * 2) ^ ((row & 7) << 4));
          *reinterpret_cast<short*>(reinterpret_cast<char*>(Pw) + byte) = f2bf(sv[ns][r]);
        }

      // ---- O += P V ----
      __builtin_amdgcn_s_setprio(1);
#pragma unroll
      for (int kk = 0; kk < 2; ++kk) {
        int kbyte = (kk * 32 + g * 8) * 2;
        int byteP = c * 128 + (kbyte ^ ((c & 7) << 4));
        short8 pf = *reinterpret_cast<const short8*>(reinterpret_cast<char*>(Pw) + byteP);
#pragma unroll
        for (int ns = 0; ns < 4; ++ns) {
          int rowV = ns * 16 + c;
          int byteV = rowV * 128 + (kbyte ^ ((rowV & 7) << 4));
          short8 vf = *reinterpret_cast<const short8*>((char*)Vl[sel] + byteV);
          acc_o[ns] = __builtin_amdgcn_mfma_f32_16x16x32_bf16(pf, vf, acc_o[ns], 0, 0, 0);
        }
      }
      __builtin_amdgcn_s_setprio(0);

      __builtin_amdgcn_sched_barrier(0);
      __builtin_amdgcn_s_barrier();
    }

    // ---- epilogue ----
#pragma unroll
    for (int ns = 0; ns < 4; ++ns)
#pragma unroll
      for (int r = 0; r < 4; ++r) {
        int row = g * 4 + r;
        int lg = l0 + wave * 16 + row;
        int d = ns * 16 + c;
        Y[((size_t)bb * LSEQ + lg) * DIM + hh * HS + d] = f2bf(acc_o[ns][r] / lrun[r]);
      }
  };

  process(31 - pair);
  process(pair);
}

// ---------------- launch ----------------

extern "C" void kernel_launch(void* const* d_in, const int* in_sizes, int n_in,
                              void* d_out, int out_size, void* d_ws, size_t ws_size,
                              hipStream_t stream)
{
  const float* x     = (const float*)d_in[0];
  const float* Wqkv  = (const float*)d_in[1];
  const float* bqkv  = (const float*)d_in[2];
  const float* Wproj = (const float*)d_in[3];
  const float* bproj = (const float*)d_in[4];
  const float* Er    = (const float*)d_in[5];

  char* ws = (char*)d_ws;
  short* xb     = (short*)(ws + 0);                       // 4096x1024 bf16 (GEMM1 input)
  short* WqkvT  = (short*)(ws + 8388608);                 // 3072x1024 bf16
  short* WprojT = (short*)(ws + 14680064);                // 1024x1024 bf16
  short* Erb    = (short*)(ws + 16777216);                // 2048x64 bf16
  short* qB     = (short*)(ws + 17039360);                // [32][2048][64] bf16
  short* kB     = (short*)(ws + 25427968);
  short* vTB    = (short*)(ws + 33816576);                // [32][64][2048] bf16 (v transposed)
  short* yB     = (short*)(ws + 42205184);                // 4096x1024 bf16

  prep_kernel<<<dim3(5248), 256, 0, stream>>>(x, Er, Wqkv, Wproj, xb, Erb, WqkvT, WprojT);

  gemm_bt_kernel<0><<<dim3(3072 / 128, 4096 / 128), 256, 0, stream>>>(
      xb, WqkvT, bqkv, 4096, 3072, 1024, qB, kB, vTB, nullptr);

  attn_kernel<<<dim3(512), 256, 0, stream>>>(qB, kB, vTB, Erb, yB);

  gemm_bt_kernel<1><<<dim3(1024 / 128, 4096 / 128), 256, 0, stream>>>(
      yB, WprojT, bproj, 4096, 1024, 1024, nullptr, nullptr, nullptr, (float*)d_out);
}